// Round 6
// baseline (543.775 us; speedup 1.0000x reference)
//
#include <hip/hip_runtime.h>

// ---------------------------------------------------------------------------
// PrimitiveDecoder: 4-layer LSTM (NH=1024), T=101 steps, tiny head.
//
// Round-6: layer-pipelined persistent kernel, value-carrying sync
// (NaN-sentinel poll on packed-f16 h replicas at MALL / system scope).
//  - 4 groups x 64 recurrence blocks (512 thr) + 65 DEDICATED head blocks
//    (grid 321, __launch_bounds__(512,2) -> guaranteed 2 blocks/CU
//    residency). Round-5 ran the head on wave 6 of group-0 blocks: two
//    blocking MALL loads (~0.5-1us) serialized into the recurrence root's
//    barrier every step.
//  - ONE barrier per step: LDS v-buffer is double-buffered by t-parity
//    (no second barrier), and every wave publishes its own packed h pair
//    directly (lanes 0-7 -> 8 replicas, one store instr) right after the
//    gate nonlinearity. Store-acks drain inside the next poll / barrier
//    wait, overlapped with detect.
//  - Fast nonlinearities: v_exp_f32/v_rcp_f32 sigmoid (4 ops) and tanh
//    (5 ops) instead of libm expf/tanhf (~300 cyc/wave -> ~120).
//  - Weights register-resident f16 (128 VGPR/lane), v_dot2_f32_f16 dot,
//    DPP wave reduction (VALU pipe only).
// ---------------------------------------------------------------------------

#define TT    101
#define NBLK  256
#define NHEAD 65
#define NTH   512
#define NREP  8
#define SLAB_U32 512                            // 1024 f16 per replica
#define STEP_U32 (NREP * SLAB_U32)              // 4096 dwords per (l,t)
#define HB16_BYTES (4 * TT * STEP_U32 * 4)      // 6,615,040 B
#define OUT_PROBS 6464
#define OUT_SAMP  6666
#define SENT 0xFFFFFFFFu

typedef _Float16 h2 __attribute__((ext_vector_type(2)));

__device__ __forceinline__ h2 mkh2(float a, float b) {
    h2 r; r.x = (_Float16)a; r.y = (_Float16)b; return r;
}
__device__ __forceinline__ unsigned pack2(float a, float b) {
    return __builtin_bit_cast(unsigned, mkh2(a, b));
}
__device__ __forceinline__ h2 as_h2(unsigned u) { return __builtin_bit_cast(h2, u); }

#if __has_builtin(__builtin_amdgcn_fdot2)
__device__ __forceinline__ float fdot2(h2 a, h2 b, float c) {
    return __builtin_amdgcn_fdot2(a, b, c, false);
}
#else
__device__ __forceinline__ float fdot2(h2 a, h2 b, float c) {
    return fmaf((float)a.x, (float)b.x, fmaf((float)a.y, (float)b.y, c));
}
#endif

// fast sigmoid / tanh via v_exp_f32 (2^x) + v_rcp_f32; |err| ~1e-6,
// threshold headroom is 160x.
#if __has_builtin(__builtin_amdgcn_exp2f) && __has_builtin(__builtin_amdgcn_rcpf)
__device__ __forceinline__ float fsigm(float x) {
    return __builtin_amdgcn_rcpf(1.f + __builtin_amdgcn_exp2f(-1.442695041f * x));
}
__device__ __forceinline__ float ftanh(float x) {
    return fmaf(-2.f, __builtin_amdgcn_rcpf(1.f + __builtin_amdgcn_exp2f(2.885390082f * x)), 1.f);
}
#else
__device__ __forceinline__ float fsigm(float x) { return 1.f / (1.f + expf(-x)); }
__device__ __forceinline__ float ftanh(float x) { return tanhf(x); }
#endif

// 16B cache-bypass load (IF$/MALL-coherent); waitcnt inside so result regs valid.
__device__ __forceinline__ uint4 load16_bypass(const uint4* p) {
    uint4 r;
    asm volatile("global_load_dwordx4 %0, %1, off sc0 sc1\n\ts_waitcnt vmcnt(0)"
                 : "=v"(r) : "v"(p) : "memory");
    return r;
}
__device__ __forceinline__ void store4_bypass(unsigned* p, unsigned v) {
    asm volatile("global_store_dword %0, %1, off sc0 sc1" :: "v"(p), "v"(v) : "memory");
}
__device__ __forceinline__ uint4 poll16(const uint4* p) {
    uint4 r = load16_bypass(p);
    while (r.x == SENT || r.y == SENT || r.z == SENT || r.w == SENT) {
        __builtin_amdgcn_s_sleep(1);
        r = load16_bypass(p);
    }
    return r;
}

// full-wave (64) sum via DPP; total broadcast via readlane(63).
__device__ __forceinline__ float wave_sum(float x) {
    int v;
    v = __builtin_amdgcn_update_dpp(0, __builtin_bit_cast(int, x), 0x111, 0xf, 0xf, false);
    x += __builtin_bit_cast(float, v);                                  // row_shr:1
    v = __builtin_amdgcn_update_dpp(0, __builtin_bit_cast(int, x), 0x112, 0xf, 0xf, false);
    x += __builtin_bit_cast(float, v);                                  // row_shr:2
    v = __builtin_amdgcn_update_dpp(0, __builtin_bit_cast(int, x), 0x114, 0xf, 0xe, false);
    x += __builtin_bit_cast(float, v);                                  // row_shr:4
    v = __builtin_amdgcn_update_dpp(0, __builtin_bit_cast(int, x), 0x118, 0xf, 0xc, false);
    x += __builtin_bit_cast(float, v);                                  // row_shr:8
    v = __builtin_amdgcn_update_dpp(0, __builtin_bit_cast(int, x), 0x142, 0xa, 0xf, false);
    x += __builtin_bit_cast(float, v);                                  // row_bcast:15
    v = __builtin_amdgcn_update_dpp(0, __builtin_bit_cast(int, x), 0x143, 0xc, 0xf, false);
    x += __builtin_bit_cast(float, v);                                  // row_bcast:31
    return __builtin_bit_cast(float, __builtin_amdgcn_readlane(__builtin_bit_cast(int, x), 63));
}

// ---------------------------------------------------------------------------
__global__ __launch_bounds__(NTH, 2) void lstm_kernel(
    const float* __restrict__ z,
    const float* __restrict__ Wih, const float* __restrict__ Whh,
    const float* __restrict__ bih, const float* __restrict__ bhh,
    const float* __restrict__ Ws,  const float* __restrict__ bs,
    const float* __restrict__ Wp,  const float* __restrict__ bp,
    unsigned* __restrict__ hb16, float* __restrict__ out)
{
    const int tid  = threadIdx.x;
    const int wv   = tid >> 6;
    const int lane = tid & 63;

    // ================= dedicated head blocks (decoupled, self-paced) ======
    if (blockIdx.x >= NBLK) {
        if (wv != 0) return;                       // 1 wave per head block
        const int hb  = blockIdx.x - NBLK;         // 0..63 states, 64 probs
        const int rep = hb & (NREP - 1);
        if (hb < 64) {
            float wr[16];
            #pragma unroll
            for (int k = 0; k < 16; ++k) wr[k] = Ws[(hb << 10) + (lane << 4) + k];
            const float bsv = bs[hb];
            for (int th = 0; th < TT; ++th) {
                const uint4* slab = (const uint4*)(hb16 + (size_t)(3 * TT + th) * STEP_U32 + rep * SLAB_U32);
                const uint4 r0 = poll16(slab + 2 * lane);
                const uint4 r1 = poll16(slab + 2 * lane + 1);
                const unsigned u8[8] = {r0.x, r0.y, r0.z, r0.w, r1.x, r1.y, r1.z, r1.w};
                float a = 0.f;
                #pragma unroll
                for (int j = 0; j < 8; ++j) {
                    const h2 p = as_h2(u8[j]);
                    a = fmaf(wr[2 * j], (float)p.x, a);
                    a = fmaf(wr[2 * j + 1], (float)p.y, a);
                }
                a = wave_sum(a);
                if (lane == 0) out[th * 64 + hb] = a + bsv;
            }
        } else {
            // samples + last-step probs are data-independent: write up front
            for (int i = lane; i < TT; i += 64) out[OUT_SAMP + i] = (i == TT - 1) ? 1.0f : 0.0f;
            if (lane == 0) { out[OUT_PROBS + 2 * (TT - 1)] = 0.f; out[OUT_PROBS + 2 * (TT - 1) + 1] = 1.f; }
            float w0[16], w1[16];
            #pragma unroll
            for (int k = 0; k < 16; ++k) {
                w0[k] = Wp[(lane << 4) + k];
                w1[k] = Wp[1024 + (lane << 4) + k];
            }
            const float bp0 = bp[0], bp1 = bp[1];
            for (int th = 0; th < TT - 1; ++th) {
                const uint4* slab = (const uint4*)(hb16 + (size_t)(3 * TT + th) * STEP_U32 + rep * SLAB_U32);
                const uint4 r0 = poll16(slab + 2 * lane);
                const uint4 r1 = poll16(slab + 2 * lane + 1);
                const unsigned u8[8] = {r0.x, r0.y, r0.z, r0.w, r1.x, r1.y, r1.z, r1.w};
                float a0 = 0.f, a1 = 0.f;
                #pragma unroll
                for (int j = 0; j < 8; ++j) {
                    const h2 p = as_h2(u8[j]);
                    a0 = fmaf(w0[2 * j], (float)p.x, a0); a0 = fmaf(w0[2 * j + 1], (float)p.y, a0);
                    a1 = fmaf(w1[2 * j], (float)p.x, a1); a1 = fmaf(w1[2 * j + 1], (float)p.y, a1);
                }
                a0 = wave_sum(a0); a1 = wave_sum(a1);
                if (lane == 0) {
                    const float l0 = a0 + bp0 + 1.0f;   // P_BIAS on logit 0
                    const float l1 = a1 + bp1;
                    const float m  = fmaxf(l0, l1);
                    const float e0 = expf(l0 - m), e1 = expf(l1 - m);
                    const float inv = 1.f / (e0 + e1);
                    out[OUT_PROBS + 2 * th]     = e0 * inv;
                    out[OUT_PROBS + 2 * th + 1] = e1 * inv;
                }
            }
        }
        return;
    }

    // ================= recurrence blocks ===================================
    const int l   = blockIdx.x >> 6;          // layer / group
    const int gb  = blockIdx.x & 63;          // block-in-group
    const int uA  = (gb << 4) + (wv << 1);    // wave's first unit

    __shared__ __align__(16) uint4 vbuf[2][256];   // double-buffered by t-parity

    // ---- weights -> registers (fp32 -> f16), chunk-aligned layout --------
    // lane covers source-unit chunks {8*lane..+7, 512+8*lane..+7} per part.
    h2 w[8][16];
    #pragma unroll
    for (int r = 0; r < 8; ++r) {
        const int u = uA + (r >> 2);
        const int g = r & 3;
        const size_t row = ((size_t)((l << 12) + (g << 10) + u)) << 10;
        const float4* pa = (const float4*)(Whh + row + (lane << 3));
        const float4* pb = (const float4*)(Whh + row + 512 + (lane << 3));
        const float4* pc = (const float4*)(Wih + row + (lane << 3));
        const float4* pd = (const float4*)(Wih + row + 512 + (lane << 3));
        float4 f;
        f = pa[0]; w[r][0]  = mkh2(f.x, f.y); w[r][1]  = mkh2(f.z, f.w);
        f = pa[1]; w[r][2]  = mkh2(f.x, f.y); w[r][3]  = mkh2(f.z, f.w);
        f = pb[0]; w[r][4]  = mkh2(f.x, f.y); w[r][5]  = mkh2(f.z, f.w);
        f = pb[1]; w[r][6]  = mkh2(f.x, f.y); w[r][7]  = mkh2(f.z, f.w);
        f = pc[0]; w[r][8]  = mkh2(f.x, f.y); w[r][9]  = mkh2(f.z, f.w);
        f = pc[1]; w[r][10] = mkh2(f.x, f.y); w[r][11] = mkh2(f.z, f.w);
        f = pd[0]; w[r][12] = mkh2(f.x, f.y); w[r][13] = mkh2(f.z, f.w);
        f = pd[1]; w[r][14] = mkh2(f.x, f.y); w[r][15] = mkh2(f.z, f.w);
    }

    float bA[4], bB[4];
    #pragma unroll
    for (int g = 0; g < 4; ++g) {
        const int iA = (l << 12) + (g << 10) + uA;
        bA[g] = bih[iA] + bhh[iA];
        bB[g] = bih[iA + 1] + bhh[iA + 1];
    }

    float cstA = 0.f, cstB = 0.f;

    #pragma unroll 1
    for (int t = 0; t < TT; ++t) {
        const bool full = (l > 0) || (t == 0);
        uint4* vh4 = vbuf[t & 1];

        // ---- staging (waves 0-3; poll IS the sync + the data load) ----
        if (wv < 2) {                              // part1: h_l(t-1)
            const int c = (wv << 6) + lane;
            if (t == 0) vh4[c] = make_uint4(0, 0, 0, 0);
            else {
                const int rep = (gb + wv) & (NREP - 1);
                const uint4* slab = (const uint4*)(hb16 + (size_t)(l * TT + t - 1) * STEP_U32 + rep * SLAB_U32);
                vh4[c] = poll16(slab + c);
            }
        } else if (wv < 4 && full) {               // part2: h_{l-1}(t) or z
            const int c = ((wv - 2) << 6) + lane;
            if (l > 0) {
                const int rep = (gb + wv) & (NREP - 1);
                const uint4* slab = (const uint4*)(hb16 + (size_t)((l - 1) * TT + t) * STEP_U32 + rep * SLAB_U32);
                vh4[128 + c] = poll16(slab + c);
            } else {                               // l==0, t==0: z
                const float4 f0 = *(const float4*)(z + (c << 3));
                const float4 f1 = *(const float4*)(z + (c << 3) + 4);
                vh4[128 + c] = make_uint4(pack2(f0.x, f0.y), pack2(f0.z, f0.w),
                                          pack2(f1.x, f1.y), pack2(f1.z, f1.w));
            }
        }
        __syncthreads();                           // the ONE barrier per step

        // ---- dot: 8 gate rows per wave ----
        float acc[8] = {0.f, 0.f, 0.f, 0.f, 0.f, 0.f, 0.f, 0.f};
        {
            const uint4 A1 = vh4[lane];
            const uint4 A2 = vh4[64 + lane];
            const unsigned a8[8] = {A1.x, A1.y, A1.z, A1.w, A2.x, A2.y, A2.z, A2.w};
            #pragma unroll
            for (int k = 0; k < 8; ++k) {
                const h2 v2 = as_h2(a8[k]);
                #pragma unroll
                for (int r = 0; r < 8; ++r) acc[r] = fdot2(w[r][k], v2, acc[r]);
            }
            if (full) {
                const uint4 B1 = vh4[128 + lane];
                const uint4 B2 = vh4[192 + lane];
                const unsigned b8[8] = {B1.x, B1.y, B1.z, B1.w, B2.x, B2.y, B2.z, B2.w};
                #pragma unroll
                for (int k = 0; k < 8; ++k) {
                    const h2 v2 = as_h2(b8[k]);
                    #pragma unroll
                    for (int r = 0; r < 8; ++r) acc[r] = fdot2(w[r][8 + k], v2, acc[r]);
                }
            }
        }

        // ---- DPP reduce -> uniform gate sums ----
        float tot[8];
        #pragma unroll
        for (int r = 0; r < 8; ++r) tot[r] = wave_sum(acc[r]);

        // ---- fast nonlinearity (uniform on all lanes) ----
        cstA = fmaf(fsigm(tot[1] + bA[1]), cstA, fsigm(tot[0] + bA[0]) * ftanh(tot[2] + bA[2]));
        cstB = fmaf(fsigm(tot[5] + bB[1]), cstB, fsigm(tot[4] + bB[0]) * ftanh(tot[6] + bB[2]));
        const float hA = fsigm(tot[3] + bA[3]) * ftanh(cstA);
        const float hB = fsigm(tot[7] + bB[3]) * ftanh(cstB);

        // ---- publish own pair to all 8 replicas (lanes 0-7, 1 store) ----
        // Ack drains inside the next poll / barrier wait (overlapped).
        const unsigned packed = pack2(hA, hB);
        if (lane < NREP) {
            unsigned* addr = hb16 + (size_t)(l * TT + t) * STEP_U32
                           + (lane << 9) + (gb << 3) + wv;
            store4_bypass(addr, packed);
        }
    }
}

// ---------------------------------------------------------------------------
extern "C" void kernel_launch(void* const* d_in, const int* in_sizes, int n_in,
                              void* d_out, int out_size, void* d_ws, size_t ws_size,
                              hipStream_t stream)
{
    const float* z   = (const float*)d_in[0];
    const float* Wih = (const float*)d_in[1];
    const float* Whh = (const float*)d_in[2];
    const float* bih = (const float*)d_in[3];
    const float* bhh = (const float*)d_in[4];
    const float* Ws  = (const float*)d_in[5];
    const float* bs  = (const float*)d_in[6];
    const float* Wp  = (const float*)d_in[7];
    const float* bp  = (const float*)d_in[8];
    float* out = (float*)d_out;

    unsigned* hb16 = (unsigned*)d_ws;

    // sentinel-init replicas (ws is re-poisoned before every timed call)
    hipMemsetAsync(hb16, 0xFF, HB16_BYTES, stream);
    lstm_kernel<<<NBLK + NHEAD, NTH, 0, stream>>>(z, Wih, Whh, bih, bhh,
                                                  Ws, bs, Wp, bp, hb16, out);
}